// Round 3
// baseline (652.767 us; speedup 1.0000x reference)
//
#include <hip/hip_runtime.h>
#include <math.h>

#define N_TOTAL 40960
#define M_EV    4096
#define KNN     32
#define FEAT    192   // CIN + 2*PDIM

typedef float f32v32 __attribute__((ext_vector_type(32)));
typedef int   i32v32 __attribute__((ext_vector_type(32)));

__device__ __forceinline__ float dot4f(float4 a, float4 b) {
    return fmaf(a.w, b.w, fmaf(a.z, b.z, fmaf(a.y, b.y, a.x * b.x)));
}

// ---------------------------------------------------------------------------
// Register-resident top-K list ops. Rescan = pairwise max tree (depth 5) +
// equality bitmask + ctz (short dep chains, no 32-deep serial max).
// ---------------------------------------------------------------------------
__device__ __forceinline__ void list_rescan(const f32v32 &ld, float &curmax, int &maxpos)
{
    float t0[16];
#pragma unroll
    for (int e = 0; e < 16; ++e) t0[e] = fmaxf(ld[2*e], ld[2*e+1]);
    float t1[8];
#pragma unroll
    for (int e = 0; e < 8; ++e) t1[e] = fmaxf(t0[2*e], t0[2*e+1]);
    float t2[4];
#pragma unroll
    for (int e = 0; e < 4; ++e) t2[e] = fmaxf(t1[2*e], t1[2*e+1]);
    float m = fmaxf(fmaxf(t2[0], t2[1]), fmaxf(t2[2], t2[3]));
    unsigned msk = 0u;
#pragma unroll
    for (int e = 0; e < 32; ++e) msk |= (ld[e] == m) ? (1u << e) : 0u;
    curmax = m;
    maxpos = (int)__builtin_ctz(msk);
}

__device__ __forceinline__ void list_insert(f32v32 &ld, i32v32 &li,
                                            float &curmax, int &maxpos,
                                            float d, int ix)
{
#pragma unroll
    for (int e = 0; e < 32; ++e) {
        bool s = (e == maxpos);
        ld[e] = s ? d  : ld[e];
        li[e] = s ? ix : li[e];
    }
    list_rescan(ld, curmax, maxpos);
}

// ---------------------------------------------------------------------------
// Kernel 1: space = x@W_space + b_space  [N,4];  prop = x@W_prop + b_prop [N,64]
// ---------------------------------------------------------------------------
__global__ __launch_bounds__(256) void k_linear(
    const float* __restrict__ x,
    const float* __restrict__ Wp, const float* __restrict__ bp,
    const float* __restrict__ Ws, const float* __restrict__ bs,
    float* __restrict__ prop, float* __restrict__ space)
{
    __shared__ float xs[16 * 64];
    const int t = threadIdx.x;
    const int rowbase = blockIdx.x * 16;

    {
        float4 v = *(const float4*)(x + rowbase * 64 + t * 4);
        *(float4*)(xs + t * 4) = v;
    }
    __syncthreads();

    const int j  = t & 63;
    const int rg = t >> 6;
    float a0 = 0.f, a1 = 0.f, a2 = 0.f, a3 = 0.f;
#pragma unroll 8
    for (int c = 0; c < 64; ++c) {
        float w = Wp[c * 64 + j];
        a0 = fmaf(xs[(rg * 4 + 0) * 64 + c], w, a0);
        a1 = fmaf(xs[(rg * 4 + 1) * 64 + c], w, a1);
        a2 = fmaf(xs[(rg * 4 + 2) * 64 + c], w, a2);
        a3 = fmaf(xs[(rg * 4 + 3) * 64 + c], w, a3);
    }
    const float bj = bp[j];
    prop[(rowbase + rg * 4 + 0) * 64 + j] = a0 + bj;
    prop[(rowbase + rg * 4 + 1) * 64 + j] = a1 + bj;
    prop[(rowbase + rg * 4 + 2) * 64 + j] = a2 + bj;
    prop[(rowbase + rg * 4 + 3) * 64 + j] = a3 + bj;

    if (t < 64) {
        const int r = t >> 2, s = t & 3;
        float a = 0.f;
#pragma unroll 8
        for (int c = 0; c < 64; ++c)
            a = fmaf(xs[r * 64 + c], Ws[c * 4 + s], a);
        space[(rowbase + r) * 4 + s] = a + bs[s];
    }
}

// ---------------------------------------------------------------------------
// Kernel 2a: per-half exact partial kNN.
// 2 blocks per 64-query group; block = 4 waves, wave w scans 512 candidates.
// Register lists (ext_vector), buffered append + wave-packed drain,
// dual-gated by min(own curmax, shared thr). Shared thr: LDS within block +
// device atomicMin across blocks (publish returns old = fresh read).
// Hierarchical in-block merge -> per-half top-32 partial to global.
// ---------------------------------------------------------------------------
#define QB    64
#define CHUNK 512
#define KTILE 64
#define QCAP  16

__global__ __launch_bounds__(256) void k_knn1(
    const float4* __restrict__ space4,
    unsigned* __restrict__ g_thr,
    float* __restrict__ part_d, int* __restrict__ part_i)
{
    __shared__ float4   s_c[4 * KTILE];      // 4096 B
    __shared__ float    s_sq[4 * KTILE];     // 1024 B
    __shared__ float    s_bd[QCAP * 256];    // 16384 B (aliased as merge pool_d)
    __shared__ int      s_bi[QCAP * 256];    // 16384 B (aliased as merge pool_i)
    __shared__ unsigned s_thr[QB];           // 256 B

    const int t = threadIdx.x;
    const int w = t >> 6;
    const int l = t & 63;
    const int grp  = blockIdx.x >> 1;
    const int half = blockIdx.x & 1;
    const int qbase = grp * QB;
    const int q = qbase + l;
    const int ebase = (qbase / M_EV) * M_EV;
    const int cbase0 = half * 2048 + w * CHUNK;   // local candidate base (this wave)

    if (t < QB) s_thr[t] = 0x7f800000u;
    __syncthreads();

    const float4 qc = space4[q];
    const float sqq = dot4f(qc, qc);

    f32v32 ld; i32v32 li;
#pragma unroll
    for (int e = 0; e < 32; ++e) { ld[e] = INFINITY; li[e] = 0; }
    float curmax = INFINITY; int maxpos = 0;
    int cnt = 0;
    float thrA = INFINITY;

    float4 nx = space4[ebase + cbase0 + l];

#pragma unroll 1
    for (int tb = 0; tb < CHUNK / KTILE; ++tb) {
        const int cb = cbase0 + tb * KTILE;
        // wave-private staging (no block barrier; same-wave lgkmcnt suffices)
        s_c[w * KTILE + l]  = nx;
        s_sq[w * KTILE + l] = dot4f(nx, nx);
        if (tb + 1 < CHUNK / KTILE)
            nx = space4[ebase + cb + KTILE + l];
        thrA = fminf(curmax, __uint_as_float(s_thr[l]));

#pragma unroll 1
        for (int jj = 0; jj < KTILE; jj += 4) {
            float d[4];
#pragma unroll
            for (int u = 0; u < 4; ++u) {
                float4 c = s_c[w * KTILE + jj + u];
                d[u] = fmaf(-2.0f, dot4f(qc, c), sqq + s_sq[w * KTILE + jj + u]);
            }
#pragma unroll
            for (int u = 0; u < 4; ++u) {
                if (d[u] < thrA) {                 // strict <: earlier idx wins ties
                    s_bd[cnt * 256 + t] = d[u];
                    s_bi[cnt * 256 + t] = cb + jj + u;
                    cnt++;
                }
            }
            if (__any(cnt > QCAP - 4)) {           // wave-collective packed drain
                float gate = fminf(curmax, __uint_as_float(s_thr[l]));
#pragma unroll 1
                for (int b = 0; b < cnt; ++b) {
                    float dd = s_bd[b * 256 + t];
                    if (dd < gate) {
                        list_insert(ld, li, curmax, maxpos, dd, s_bi[b * 256 + t]);
                        gate = fminf(curmax, gate);
                    }
                }
                cnt = 0;
                if (curmax < 3.0e38f) {
                    unsigned mb = __float_as_uint(fmaxf(curmax, 0.0f));
                    atomicMin(&s_thr[l], mb);
                    unsigned old = atomicMin(&g_thr[q], mb);   // publish + fresh read
                    atomicMin(&s_thr[l], old);
                }
                thrA = fminf(curmax, __uint_as_float(s_thr[l]));
            }
        }
    }
    {   // final drain
        float gate = fminf(curmax, __uint_as_float(s_thr[l]));
#pragma unroll 1
        for (int b = 0; b < cnt; ++b) {
            float dd = s_bd[b * 256 + t];
            if (dd < gate) {
                list_insert(ld, li, curmax, maxpos, dd, s_bi[b * 256 + t]);
                gate = fminf(curmax, gate);
            }
        }
    }

    // ---- hierarchical in-block merge (pool aliases s_bd/s_bi) ----
    __syncthreads();                               // scan buffers now dead
    if (w >= 2) {
#pragma unroll
        for (int e = 0; e < 32; ++e) {
            s_bd[((w - 2) * 32 + e) * 64 + l] = ld[e];
            s_bi[((w - 2) * 32 + e) * 64 + l] = li[e];
        }
    }
    __syncthreads();
    if (w < 2) {                                   // wave0<-wave2, wave1<-wave3
#pragma unroll 1
        for (int j = 0; j < 32; ++j) {
            float dd = s_bd[(w * 32 + j) * 64 + l];
            if (dd < curmax)
                list_insert(ld, li, curmax, maxpos, dd, s_bi[(w * 32 + j) * 64 + l]);
        }
    }
    __syncthreads();
    if (w == 1) {
#pragma unroll
        for (int e = 0; e < 32; ++e) {
            s_bd[e * 64 + l] = ld[e];
            s_bi[e * 64 + l] = li[e];
        }
    }
    __syncthreads();
    if (w == 0) {
#pragma unroll 1
        for (int j = 0; j < 32; ++j) {
            float dd = s_bd[j * 64 + l];
            if (dd < curmax)
                list_insert(ld, li, curmax, maxpos, dd, s_bi[j * 64 + l]);
        }
        const int q2h = (q << 1) | half;
#pragma unroll
        for (int e = 0; e < 32; ++e) {             // transposed for coalesced phase-2
            part_d[e * (N_TOTAL * 2) + q2h] = ld[e];
            part_i[e * (N_TOTAL * 2) + q2h] = ebase + li[e];
        }
    }
}

// ---------------------------------------------------------------------------
// Kernel 2b: merge the two per-half top-32 partials -> exact top-32 + weights.
// ---------------------------------------------------------------------------
__global__ __launch_bounds__(256) void k_knn2(
    const float* __restrict__ part_d, const int* __restrict__ part_i,
    int* __restrict__ knn_idx, float* __restrict__ knn_w)
{
    const int q  = blockIdx.x * 256 + threadIdx.x;
    const int q2 = q << 1;

    f32v32 ld; i32v32 li;
#pragma unroll
    for (int e = 0; e < 32; ++e) {                 // fill from half 0 (no rescans)
        ld[e] = part_d[e * (N_TOTAL * 2) + q2];
        li[e] = part_i[e * (N_TOTAL * 2) + q2];
    }
    float curmax; int maxpos;
    list_rescan(ld, curmax, maxpos);

#pragma unroll 1
    for (int j = 0; j < 32; ++j) {                 // gated inserts from half 1
        float dd = part_d[j * (N_TOTAL * 2) + q2 + 1];
        if (dd < curmax)
            list_insert(ld, li, curmax, maxpos, dd, part_i[j * (N_TOTAL * 2) + q2 + 1]);
    }

#pragma unroll
    for (int e = 0; e < 32; ++e) {
        knn_idx[e * N_TOTAL + q] = li[e];
        knn_w[e * N_TOTAL + q]   = __expf(-10.0f * fmaxf(ld[e], 0.0f));
    }
}

// ---------------------------------------------------------------------------
// Kernel 3: weighted gather + mean/max over K
// ---------------------------------------------------------------------------
__global__ __launch_bounds__(256) void k_agg(
    const float* __restrict__ prop,
    const int* __restrict__ knn_idx, const float* __restrict__ knn_w,
    float* __restrict__ fmean, float* __restrict__ fmax)
{
    const int t = threadIdx.x;
    const int p = t & 63;
    const int q = blockIdx.x * 4 + (t >> 6);

    float acc = 0.f, mx = -INFINITY;
#pragma unroll 8
    for (int e = 0; e < KNN; ++e) {
        int   ix = knn_idx[e * N_TOTAL + q];
        float w  = knn_w[e * N_TOTAL + q];
        float g  = w * prop[(size_t)ix * 64 + p];
        acc += g;
        mx = fmaxf(mx, g);
    }
    fmean[(size_t)q * 64 + p] = acc * (1.0f / 32.0f);
    fmax[(size_t)q * 64 + p]  = mx;
}

// ---------------------------------------------------------------------------
// Kernel 4: out = relu([x | fmean | fmax] @ W_out + b_out)
// ---------------------------------------------------------------------------
__global__ __launch_bounds__(256) void k_out(
    const float* __restrict__ x,
    const float* __restrict__ fmean, const float* __restrict__ fmax,
    const float* __restrict__ Wo, const float* __restrict__ bo,
    float* __restrict__ out)
{
    __shared__ float fs[16 * FEAT];
    const int t = threadIdx.x;
    const int qbase = blockIdx.x * 16;

#pragma unroll
    for (int u = 0; u < 12; ++u) {
        int f = u * 256 + t;
        int r = f / FEAT;
        int i = f - r * FEAT;
        float v;
        if (i < 64)        v = x[(size_t)(qbase + r) * 64 + i];
        else if (i < 128)  v = fmean[(size_t)(qbase + r) * 64 + (i - 64)];
        else               v = fmax[(size_t)(qbase + r) * 64 + (i - 128)];
        fs[f] = v;
    }
    __syncthreads();

    const int c  = t & 127;
    const int rg = t >> 7;
    float acc[8] = {0.f, 0.f, 0.f, 0.f, 0.f, 0.f, 0.f, 0.f};

#pragma unroll 4
    for (int i = 0; i < FEAT; ++i) {
        float w = Wo[i * 128 + c];
#pragma unroll
        for (int r = 0; r < 8; ++r)
            acc[r] = fmaf(fs[(rg * 8 + r) * FEAT + i], w, acc[r]);
    }
    const float bc = bo[c];
#pragma unroll
    for (int r = 0; r < 8; ++r)
        out[(size_t)(qbase + rg * 8 + r) * 128 + c] = fmaxf(acc[r] + bc, 0.0f);
}

// ---------------------------------------------------------------------------
extern "C" void kernel_launch(void* const* d_in, const int* in_sizes, int n_in,
                              void* d_out, int out_size, void* d_ws, size_t ws_size,
                              hipStream_t stream) {
    const float* x  = (const float*)d_in[0];
    const float* Ws = (const float*)d_in[2];
    const float* bs = (const float*)d_in[3];
    const float* Wp = (const float*)d_in[4];
    const float* bp = (const float*)d_in[5];
    const float* Wo = (const float*)d_in[6];
    const float* bo = (const float*)d_in[7];
    float* out = (float*)d_out;

    float* space = (float*)d_ws;                         // N*4
    float* prop  = space + (size_t)N_TOTAL * 4;          // N*64
    int*   kidx  = (int*)(prop + (size_t)N_TOTAL * 64);  // 32*N
    float* kw    = (float*)(kidx + (size_t)KNN * N_TOTAL);
    float* fmean = kw + (size_t)KNN * N_TOTAL;           // N*64
    float* fmax  = fmean + (size_t)N_TOTAL * 64;         // N*64
    // partials alias fmean/fmax (dead until k_agg; 2*32*N*4 B = exactly N*64 fl each)
    float*    part_d = fmean;
    int*      part_i = (int*)fmax;
    unsigned* g_thr  = (unsigned*)(fmax + (size_t)N_TOTAL * 64);  // N*4 B

    hipMemsetAsync(g_thr, 0x7f, N_TOTAL * sizeof(unsigned), stream); // ~3.39e38

    k_linear<<<N_TOTAL / 16, 256, 0, stream>>>(x, Wp, bp, Ws, bs, prop, space);
    k_knn1  <<<(N_TOTAL / QB) * 2, 256, 0, stream>>>((const float4*)space, g_thr, part_d, part_i);
    k_knn2  <<<N_TOTAL / 256, 256, 0, stream>>>(part_d, part_i, kidx, kw);
    k_agg   <<<N_TOTAL / 4, 256, 0, stream>>>(prop, kidx, kw, fmean, fmax);
    k_out   <<<N_TOTAL / 16, 256, 0, stream>>>(x, fmean, fmax, Wo, bo, out);
}